// Round 7
// baseline (512.452 us; speedup 1.0000x reference)
//
#include <hip/hip_runtime.h>
#include <hip/hip_bf16.h>
#include <math.h>

#define NEG_SLOPE 0.2f

// ---------------- GEMM f32: 64x64 tile, BK=32, 256 thr, 4x4 micro ----------
#define BM 64
#define BN 64
#define BK 32

__global__ __launch_bounds__(256) void gemm_f32(const float* __restrict__ A,
                                                const float* __restrict__ B,
                                                float* __restrict__ C,
                                                int M, int N, int K) {
  __shared__ float As[BK][BM + 4];   // +4 pad: 16B-aligned rows, conflict break
  __shared__ float Bs[BK][BN];
  const int tid = threadIdx.x;
  const int bm = blockIdx.x * BM;
  const int bn = blockIdx.y * BN;
  const int tx = tid & 15;
  const int ty = tid >> 4;
  float acc[4][4] = {};
  for (int k0 = 0; k0 < K; k0 += BK) {
    // A tile: 64 rows x 32 K, float4 along K (512 float4s, 2 per thread)
    #pragma unroll
    for (int i = tid; i < BM * BK / 4; i += 256) {
      int r = i >> 3;              // BK/4 = 8 float4 per row
      int c4 = i & 7;
      int gr = bm + r;
      float4 v = make_float4(0.f, 0.f, 0.f, 0.f);
      if (gr < M) v = *reinterpret_cast<const float4*>(&A[(size_t)gr * K + k0 + c4 * 4]);
      As[c4 * 4 + 0][r] = v.x;
      As[c4 * 4 + 1][r] = v.y;
      As[c4 * 4 + 2][r] = v.z;
      As[c4 * 4 + 3][r] = v.w;
    }
    // B tile: 32 K x 64 N, float4 along N (512 float4s)
    #pragma unroll
    for (int i = tid; i < BK * BN / 4; i += 256) {
      int r = i >> 4;              // BN/4 = 16 float4 per row
      int c4 = i & 15;
      float4 v = *reinterpret_cast<const float4*>(&B[(size_t)(k0 + r) * N + bn + c4 * 4]);
      *reinterpret_cast<float4*>(&Bs[r][c4 * 4]) = v;
    }
    __syncthreads();
    #pragma unroll
    for (int kk = 0; kk < BK; ++kk) {
      float4 a4 = *reinterpret_cast<const float4*>(&As[kk][ty * 4]);
      float4 b4 = *reinterpret_cast<const float4*>(&Bs[kk][tx * 4]);
      float a[4] = {a4.x, a4.y, a4.z, a4.w};
      float b[4] = {b4.x, b4.y, b4.z, b4.w};
      #pragma unroll
      for (int i = 0; i < 4; ++i)
        #pragma unroll
        for (int j = 0; j < 4; ++j) acc[i][j] += a[i] * b[j];
    }
    __syncthreads();
  }
  #pragma unroll
  for (int i = 0; i < 4; ++i) {
    int gr = bm + ty * 4 + i;
    if (gr < M) {
      float4 v = make_float4(acc[i][0], acc[i][1], acc[i][2], acc[i][3]);
      *reinterpret_cast<float4*>(&C[(size_t)gr * N + bn + tx * 4]) = v;
    }
  }
}

// ---------------- node init: self-loop degree + cursor ----------------------
__global__ void init_nodes(int* deg, int* cursor, int N) {
  int n = blockIdx.x * blockDim.x + threadIdx.x;
  if (n >= N) return;
  deg[n] = 1;        // self loop
  cursor[n] = 0;
}

// ---------------- degree count over real edges ------------------------------
__global__ void count_deg(const int* __restrict__ ei, int E, int* __restrict__ deg) {
  int i = blockIdx.x * blockDim.x + threadIdx.x;
  if (i >= E) return;
  atomicAdd(&deg[ei[E + i]], 1);     // ei[E + i] = dst
}

// ---------------- exclusive scan of degrees (single block) ------------------
__global__ __launch_bounds__(1024) void scan_deg(const int* __restrict__ deg,
                                                 int* __restrict__ off, int N) {
  __shared__ int partial[1024];
  int tid = threadIdx.x;
  int chunk = (N + 1023) / 1024;
  int start = tid * chunk;
  int end = min(start + chunk, N);
  int sum = 0;
  for (int i = start; i < end; ++i) sum += deg[i];
  partial[tid] = sum;
  __syncthreads();
  for (int s = 1; s < 1024; s <<= 1) {
    int v = (tid >= s) ? partial[tid - s] : 0;
    __syncthreads();
    partial[tid] += v;
    __syncthreads();
  }
  int run = (tid == 0) ? 0 : partial[tid - 1];
  for (int i = start; i < end; ++i) { off[i] = run; run += deg[i]; }
  if (tid == 1023) off[N] = partial[1023];
}

// ---------------- CSR fill (src list grouped by dst) ------------------------
__global__ void fill_csr(const int* __restrict__ ei, int E, int N,
                         const int* __restrict__ off, int* __restrict__ cursor,
                         int* __restrict__ srcs) {
  int i = blockIdx.x * blockDim.x + threadIdx.x;
  int total = E + N;
  if (i >= total) return;
  int s, d;
  if (i < E) { s = ei[i]; d = ei[E + i]; }
  else       { s = d = i - E; }            // self loops
  int pos = off[d] + atomicAdd(&cursor[d], 1);
  srcs[pos] = s;
}

// ---------------- per-(node,head) attention logits, layer 1 -----------------
__global__ void scores1(const float* __restrict__ h1, const float* __restrict__ att_s,
                        const float* __restrict__ att_d, float* __restrict__ a_s,
                        float* __restrict__ a_d, int N) {
  int idx = blockIdx.x * blockDim.x + threadIdx.x;
  if (idx >= N * 8) return;
  int hh = idx & 7;
  const float4* row = reinterpret_cast<const float4*>(h1 + (size_t)(idx >> 3) * 256 + hh * 32);
  const float4* as4 = reinterpret_cast<const float4*>(att_s) + hh * 8;
  const float4* ad4 = reinterpret_cast<const float4*>(att_d) + hh * 8;
  float ss = 0.f, dd = 0.f;
  #pragma unroll
  for (int c = 0; c < 8; ++c) {
    float4 v = row[c], s4 = as4[c], d4 = ad4[c];
    ss += v.x * s4.x + v.y * s4.y + v.z * s4.z + v.w * s4.w;
    dd += v.x * d4.x + v.y * d4.y + v.z * d4.z + v.w * d4.w;
  }
  a_s[idx] = ss;
  a_d[idx] = dd;
}

// ------ layer-1 aggregation, fused softmax: 1 wave per node, 4 nodes/block --
// lane -> channels lane*4..lane*4+3, head = lane>>3. Per edge: recompute
// w = exp(leaky(a_s[src]+a_d[dst])); acc += w * h1[src]; sw += w.
__global__ __launch_bounds__(256) void aggregate1(const int* __restrict__ off,
                                                  const int* __restrict__ srcs,
                                                  const float* __restrict__ a_s,
                                                  const float* __restrict__ a_d,
                                                  const float* __restrict__ h1,
                                                  const float* __restrict__ b1,
                                                  float* __restrict__ y1, int N) {
  int n = blockIdx.x * 4 + (threadIdx.x >> 6);
  if (n >= N) return;
  int lane = threadIdx.x & 63;
  int hh = lane >> 3;
  float adh = a_d[n * 8 + hh];
  int beg = off[n], end = off[n + 1];
  float4 acc = make_float4(0.f, 0.f, 0.f, 0.f);
  float sw = 0.f;
  int p = beg;
  for (; p + 4 <= end; p += 4) {       // 4 coalesced 1KB row-gathers in flight
    int s0 = srcs[p], s1 = srcs[p + 1], s2 = srcs[p + 2], s3 = srcs[p + 3];
    const float4 v0 = *reinterpret_cast<const float4*>(h1 + (size_t)s0 * 256 + lane * 4);
    const float4 v1 = *reinterpret_cast<const float4*>(h1 + (size_t)s1 * 256 + lane * 4);
    const float4 v2 = *reinterpret_cast<const float4*>(h1 + (size_t)s2 * 256 + lane * 4);
    const float4 v3 = *reinterpret_cast<const float4*>(h1 + (size_t)s3 * 256 + lane * 4);
    float e0 = a_s[s0 * 8 + hh] + adh;
    float e1 = a_s[s1 * 8 + hh] + adh;
    float e2 = a_s[s2 * 8 + hh] + adh;
    float e3 = a_s[s3 * 8 + hh] + adh;
    e0 = e0 > 0.f ? e0 : NEG_SLOPE * e0;
    e1 = e1 > 0.f ? e1 : NEG_SLOPE * e1;
    e2 = e2 > 0.f ? e2 : NEG_SLOPE * e2;
    e3 = e3 > 0.f ? e3 : NEG_SLOPE * e3;
    float w0 = __expf(e0), w1 = __expf(e1), w2 = __expf(e2), w3 = __expf(e3);
    sw += (w0 + w1) + (w2 + w3);
    acc.x += w0 * v0.x + w1 * v1.x + w2 * v2.x + w3 * v3.x;
    acc.y += w0 * v0.y + w1 * v1.y + w2 * v2.y + w3 * v3.y;
    acc.z += w0 * v0.z + w1 * v1.z + w2 * v2.z + w3 * v3.z;
    acc.w += w0 * v0.w + w1 * v1.w + w2 * v2.w + w3 * v3.w;
  }
  if (p + 2 <= end) {                  // 2-deep tail
    int s0 = srcs[p], s1 = srcs[p + 1];
    const float4 v0 = *reinterpret_cast<const float4*>(h1 + (size_t)s0 * 256 + lane * 4);
    const float4 v1 = *reinterpret_cast<const float4*>(h1 + (size_t)s1 * 256 + lane * 4);
    float e0 = a_s[s0 * 8 + hh] + adh;
    float e1 = a_s[s1 * 8 + hh] + adh;
    e0 = e0 > 0.f ? e0 : NEG_SLOPE * e0;
    e1 = e1 > 0.f ? e1 : NEG_SLOPE * e1;
    float w0 = __expf(e0), w1 = __expf(e1);
    sw += w0 + w1;
    acc.x += w0 * v0.x + w1 * v1.x;
    acc.y += w0 * v0.y + w1 * v1.y;
    acc.z += w0 * v0.z + w1 * v1.z;
    acc.w += w0 * v0.w + w1 * v1.w;
    p += 2;
  }
  if (p < end) {
    int s0 = srcs[p];
    const float4 v0 = *reinterpret_cast<const float4*>(h1 + (size_t)s0 * 256 + lane * 4);
    float e0 = a_s[s0 * 8 + hh] + adh;
    e0 = e0 > 0.f ? e0 : NEG_SLOPE * e0;
    float w0 = __expf(e0);
    sw += w0;
    acc.x += w0 * v0.x; acc.y += w0 * v0.y; acc.z += w0 * v0.z; acc.w += w0 * v0.w;
  }
  float inv = 1.f / (sw + 1e-16f);
  float4 b = reinterpret_cast<const float4*>(b1)[lane];
  float4 r;
  r.x = acc.x * inv + b.x;
  r.y = acc.y * inv + b.y;
  r.z = acc.z * inv + b.z;
  r.w = acc.w * inv + b.w;
  r.x = r.x > 0.f ? r.x : (__expf(r.x) - 1.f);   // ELU
  r.y = r.y > 0.f ? r.y : (__expf(r.y) - 1.f);
  r.z = r.z > 0.f ? r.z : (__expf(r.z) - 1.f);
  r.w = r.w > 0.f ? r.w : (__expf(r.w) - 1.f);
  *reinterpret_cast<float4*>(y1 + (size_t)n * 256 + lane * 4) = r;
}

// ---------------- per-node attention logits, layer 2 ------------------------
__global__ void scores2(const float* __restrict__ h2, const float* __restrict__ att_s,
                        const float* __restrict__ att_d, float* __restrict__ a_s,
                        float* __restrict__ a_d, int N) {
  int n = blockIdx.x * blockDim.x + threadIdx.x;
  if (n >= N) return;
  const float4* row = reinterpret_cast<const float4*>(h2 + (size_t)n * 64);
  const float4* as4 = reinterpret_cast<const float4*>(att_s);
  const float4* ad4 = reinterpret_cast<const float4*>(att_d);
  float ss = 0.f, dd = 0.f;
  #pragma unroll
  for (int c = 0; c < 16; ++c) {
    float4 v = row[c], s4 = as4[c], d4 = ad4[c];
    ss += v.x * s4.x + v.y * s4.y + v.z * s4.z + v.w * s4.w;
    dd += v.x * d4.x + v.y * d4.y + v.z * d4.z + v.w * d4.w;
  }
  a_s[n] = ss;
  a_d[n] = dd;
}

// ------ layer-2 aggregation, fused softmax: 1 wave/node, lane = channel -----
// Zero divergence: each wave owns one node, lane c accumulates channel c.
__global__ __launch_bounds__(256) void aggregate2(const int* __restrict__ off,
                                                  const int* __restrict__ srcs,
                                                  const float* __restrict__ a_s,
                                                  const float* __restrict__ a_d,
                                                  const float* __restrict__ h2,
                                                  const float* __restrict__ b2,
                                                  float* __restrict__ out, int N) {
  int n = blockIdx.x * 4 + (threadIdx.x >> 6);
  if (n >= N) return;
  int c = threadIdx.x & 63;            // channel 0..63
  float ad = a_d[n];
  int beg = off[n], end = off[n + 1];
  float acc = 0.f;
  float sw = 0.f;
  int p = beg;
  for (; p + 4 <= end; p += 4) {       // 4 coalesced 256B row-gathers in flight
    int s0 = srcs[p], s1 = srcs[p + 1], s2 = srcs[p + 2], s3 = srcs[p + 3];
    float v0 = h2[(size_t)s0 * 64 + c];
    float v1 = h2[(size_t)s1 * 64 + c];
    float v2 = h2[(size_t)s2 * 64 + c];
    float v3 = h2[(size_t)s3 * 64 + c];
    float e0 = a_s[s0] + ad;
    float e1 = a_s[s1] + ad;
    float e2 = a_s[s2] + ad;
    float e3 = a_s[s3] + ad;
    e0 = e0 > 0.f ? e0 : NEG_SLOPE * e0;
    e1 = e1 > 0.f ? e1 : NEG_SLOPE * e1;
    e2 = e2 > 0.f ? e2 : NEG_SLOPE * e2;
    e3 = e3 > 0.f ? e3 : NEG_SLOPE * e3;
    float w0 = __expf(e0), w1 = __expf(e1), w2 = __expf(e2), w3 = __expf(e3);
    sw += (w0 + w1) + (w2 + w3);
    acc += w0 * v0 + w1 * v1 + w2 * v2 + w3 * v3;
  }
  for (; p + 2 <= end; p += 2) {       // 2-deep tail
    int s0 = srcs[p], s1 = srcs[p + 1];
    float v0 = h2[(size_t)s0 * 64 + c];
    float v1 = h2[(size_t)s1 * 64 + c];
    float e0 = a_s[s0] + ad;
    float e1 = a_s[s1] + ad;
    e0 = e0 > 0.f ? e0 : NEG_SLOPE * e0;
    e1 = e1 > 0.f ? e1 : NEG_SLOPE * e1;
    float w0 = __expf(e0), w1 = __expf(e1);
    sw += w0 + w1;
    acc += w0 * v0 + w1 * v1;
  }
  if (p < end) {
    int s0 = srcs[p];
    float v0 = h2[(size_t)s0 * 64 + c];
    float e0 = a_s[s0] + ad;
    e0 = e0 > 0.f ? e0 : NEG_SLOPE * e0;
    float w0 = __expf(e0);
    sw += w0;
    acc += w0 * v0;
  }
  out[(size_t)n * 64 + c] = acc / (sw + 1e-16f) + b2[c];   // heads=1: mean==id
}

extern "C" void kernel_launch(void* const* d_in, const int* in_sizes, int n_in,
                              void* d_out, int out_size, void* d_ws, size_t ws_size,
                              hipStream_t stream) {
  const float* x   = (const float*)d_in[0];
  const int*   ei  = (const int*)d_in[1];
  const float* W1  = (const float*)d_in[2];
  const float* as1 = (const float*)d_in[3];
  const float* ad1 = (const float*)d_in[4];
  const float* b1  = (const float*)d_in[5];
  const float* W2  = (const float*)d_in[6];
  const float* as2 = (const float*)d_in[7];
  const float* ad2 = (const float*)d_in[8];
  const float* b2  = (const float*)d_in[9];
  float* out = (float*)d_out;

  const int N = in_sizes[0] / 128;   // 50000
  const int E = in_sizes[1] / 2;     // 800000
  const int T = E + N;               // edge slots incl self loops

  // -------- workspace layout (~108 MB peak, layer-2 aliases layer-1) --------
  char* w = (char*)d_ws;
  size_t o = 0;
  auto alloc = [&](size_t bytes) -> void* {
    void* p = w + o;
    o += (bytes + 255) & ~(size_t)255;
    return p;
  };
  float* h1   = (float*)alloc((size_t)N * 256 * 4);   // dead after aggregate1
  float* y1   = (float*)alloc((size_t)N * 256 * 4);
  float* a_s1 = (float*)alloc((size_t)N * 8 * 4);     // dead after aggregate1
  float* a_d1 = (float*)alloc((size_t)N * 8 * 4);     // dead after aggregate1
  int*   deg  = (int*)alloc((size_t)N * 4);
  int*   off  = (int*)alloc((size_t)(N + 1) * 4);
  int*   cur  = (int*)alloc((size_t)N * 4);
  int*   srcs = (int*)alloc((size_t)T * 4);
  // layer-2 aliases (strictly after last read of the aliased buffer):
  float* h2   = h1;                   // 12.8 MB into h1's 51.2 MB
  float* a_s2 = a_s1;
  float* a_d2 = a_d1;

  // -------- CSR build (shared by both layers) --------
  init_nodes<<<(N + 255) / 256, 256, 0, stream>>>(deg, cur, N);
  count_deg<<<(E + 255) / 256, 256, 0, stream>>>(ei, E, deg);
  scan_deg<<<1, 1024, 0, stream>>>(deg, off, N);
  fill_csr<<<(T + 255) / 256, 256, 0, stream>>>(ei, E, N, off, cur, srcs);

  // -------- layer 1 --------
  dim3 g1((N + BM - 1) / BM, 256 / BN);
  gemm_f32<<<g1, 256, 0, stream>>>(x, W1, h1, N, 256, 128);
  scores1<<<(N * 8 + 255) / 256, 256, 0, stream>>>(h1, as1, ad1, a_s1, a_d1, N);
  aggregate1<<<(N + 3) / 4, 256, 0, stream>>>(off, srcs, a_s1, a_d1, h1, b1, y1, N);

  // -------- layer 2 --------
  dim3 g2((N + BM - 1) / BM, 64 / BN);
  gemm_f32<<<g2, 256, 0, stream>>>(y1, W2, h2, N, 64, 256);
  scores2<<<(N + 255) / 256, 256, 0, stream>>>(h2, as2, ad2, a_s2, a_d2, N);
  aggregate2<<<(N + 3) / 4, 256, 0, stream>>>(off, srcs, a_s2, a_d2, h2, b2, out, N);
}